// Round 9
// baseline (1976.663 us; speedup 1.0000x reference)
//
#include <hip/hip_runtime.h>
#include <hip/hip_fp16.h>
#include <cstdint>
#include <cstddef>

// Problem constants: B=32, s1(seq)=325, s2(T)=12, D=128, H=8, hd=16
#define GRU_ROWS 384   // B * s2 = 32*12 independent GRU sequences per GRU
#define SEQ      325   // GRU sequence length (s1)
#define D3       384   // 3*D gate width
#define DD       128   // hidden dim

__device__ __forceinline__ float sigf(float x) { return 1.f / (1.f + __expf(-x)); }
__device__ __forceinline__ float tanh_fast(float x) {
  const float e = __expf(-2.f * fabsf(x));
  const float t = (1.f - e) / (1.f + e);
  return copysignf(t, x);
}

template <typename T> __device__ __forceinline__ float ldf(const T* p);
template <> __device__ __forceinline__ float ldf<float>(const float* p) { return *p; }
template <> __device__ __forceinline__ float ldf<__half>(const __half* p) { return __half2float(*p); }
template <typename T> __device__ __forceinline__ void stf(T* p, float v);
template <> __device__ __forceinline__ void stf<float>(float* p, float v) { *p = v; }
template <> __device__ __forceinline__ void stf<__half>(__half* p, float v) { *p = __float2half(v); }

// ---------------------------------------------------------------------------
// K1: input projection GEMM.  xw[m][g] = sum_d X[m][d]*Wih[g][d] + bih[g]
// X: [124800, 128] row-major. The reference's reshape(B*s2, s1, D) is a pure
// row-major rechunk of the [B,N,T,D] buffer, so m = row*SEQ + p is the flat
// storage row directly. Wih: [384, 128] row-major.
// Tile 128(M) x 64(N), K staged in halves of 64. 256 threads, each 8x4 outputs.
// ---------------------------------------------------------------------------
template <typename XW_T>
__global__ __launch_bounds__(256) void k1_inproj(const float* __restrict__ X,
                                                 const float* __restrict__ Wih,
                                                 const float* __restrict__ bih,
                                                 XW_T* __restrict__ xw) {
  __shared__ float As[128][65];  // +1 pad -> conflict-free / 2-way reads
  __shared__ float Bs[64][65];
  const int tid = threadIdx.x;
  const int m0 = blockIdx.x * 128;
  const int n0 = blockIdx.y * 64;
  const int tr = tid >> 4;   // 0..15 -> 8 rows each
  const int tc = tid & 15;   // 0..15 -> 4 cols each
  float acc[8][4] = {};

  for (int kc = 0; kc < 128; kc += 64) {
    __syncthreads();
#pragma unroll
    for (int ps = 0; ps < 8; ps++) {
      const int r = (tid >> 4) + ps * 16;
      const int c = (tid & 15) * 4;
      const float4 a = *(const float4*)(X + (size_t)(m0 + r) * 128 + kc + c);
      As[r][c + 0] = a.x; As[r][c + 1] = a.y; As[r][c + 2] = a.z; As[r][c + 3] = a.w;
    }
#pragma unroll
    for (int ps = 0; ps < 4; ps++) {
      const int r = (tid >> 4) + ps * 16;
      const int c = (tid & 15) * 4;
      const float4 b = *(const float4*)(Wih + (size_t)(n0 + r) * 128 + kc + c);
      Bs[r][c + 0] = b.x; Bs[r][c + 1] = b.y; Bs[r][c + 2] = b.z; Bs[r][c + 3] = b.w;
    }
    __syncthreads();
#pragma unroll 4
    for (int k = 0; k < 64; k++) {
      float a[8], b[4];
#pragma unroll
      for (int i = 0; i < 8; i++) a[i] = As[tr * 8 + i][k];
#pragma unroll
      for (int j = 0; j < 4; j++) b[j] = Bs[tc * 4 + j][k];
#pragma unroll
      for (int i = 0; i < 8; i++)
#pragma unroll
        for (int j = 0; j < 4; j++) acc[i][j] = fmaf(a[i], b[j], acc[i][j]);
    }
  }
  float bi[4];
#pragma unroll
  for (int j = 0; j < 4; j++) bi[j] = bih[n0 + tc * 4 + j];
#pragma unroll
  for (int i = 0; i < 8; i++) {
    XW_T* op = xw + (size_t)(m0 + tr * 8 + i) * D3 + n0 + tc * 4;
#pragma unroll
    for (int j = 0; j < 4; j++) stf(op + j, acc[i][j] + bi[j]);
  }
}

// ---------------------------------------------------------------------------
// K2: sequential GRU scan. Block = 768 threads = 2 rows x 384 gate-threads.
// Thread owns gate g of its row: Whh[g][:] lives in 128 VGPRs; h broadcast
// from LDS; xw prefetched one step ahead. 2 barriers per step.
// Gate order (r,z,n): g<128 r, 128..255 z, 256..383 n (hn kept separate).
// y layout: [b][p][j][d] = [32][325][12][128] == the reference's
// post-transpose [B, s1, s2, D]: y[b][p][j] = gru_out[row=b*12+j][p].
// ---------------------------------------------------------------------------
template <typename XW_T, typename Y_T>
__global__ __launch_bounds__(768) void k2_scan(const XW_T* __restrict__ xw,
                                               const float* __restrict__ Whh,
                                               const float* __restrict__ bhh,
                                               Y_T* __restrict__ y) {
  __shared__ __align__(16) float h_lds[2][DD];
  __shared__ float pre[2][512];
  const int t = threadIdx.x;
  const int sel = (t >= 384) ? 1 : 0;
  const int g = t - sel * 384;
  const int row = blockIdx.x * 2 + sel;
  const int bb = row / 12, jj = row % 12;

  float4 w4[32];
#pragma unroll
  for (int i = 0; i < 32; i++) w4[i] = *(const float4*)(Whh + (size_t)g * DD + i * 4);
  const float bh = bhh[g];
  if (g < DD) h_lds[sel][g] = 0.f;

  const XW_T* xp = xw + (size_t)row * SEQ * D3 + g;
  float xw_cur = ldf(xp);
  Y_T* yp = y + ((size_t)bb * SEQ * 12 + jj) * DD + g;  // used only when g<128
  __syncthreads();

  for (int p = 0; p < SEQ; p++) {
    // Prefetch next step's xw. At p=SEQ-1 this reads one row past this row's
    // xw slice: in-bounds of d_ws (slop reserved), value discarded.
    const float xw_next = ldf(xp + (size_t)(p + 1) * D3);

    // gh[g] = Whh[g][:] . h  (4 partial chains to break FMA latency)
    const float4* h4 = (const float4*)h_lds[sel];
    float a0 = 0.f, a1 = 0.f, a2 = 0.f, a3 = 0.f;
#pragma unroll
    for (int i = 0; i < 32; i++) {
      const float4 hv = h4[i];
      a0 = fmaf(w4[i].x, hv.x, a0);
      a1 = fmaf(w4[i].y, hv.y, a1);
      a2 = fmaf(w4[i].z, hv.z, a2);
      a3 = fmaf(w4[i].w, hv.w, a3);
    }
    const float hg = (a0 + a1) + (a2 + a3) + bh;

    if (g < 256) {
      pre[sel][g] = xw_cur + hg;          // full preact for r,z
    } else {
      pre[sel][g] = hg;                   // hn (recurrent part incl. bhh)
      pre[sel][g + 128] = xw_cur;         // xn (input part incl. bih)
    }
    __syncthreads();

    if (g < DD) {
      const float r = sigf(pre[sel][g]);
      const float z = sigf(pre[sel][DD + g]);
      const float n = tanh_fast(pre[sel][384 + g] + r * pre[sel][256 + g]);
      const float hold = h_lds[sel][g];
      const float hnew = (1.f - z) * n + z * hold;
      h_lds[sel][g] = hnew;
      stf(yp + (size_t)p * 12 * DD, hnew);
    }
    __syncthreads();
    xw_cur = xw_next;
  }
}

// ---------------------------------------------------------------------------
// K3: attention + output projection, one WG per (b, p). q/k/v/ao staged in LDS.
//
// BIAS INDEX (the r7 absmax-1.73 bug, fixed): the reference's
// rb = broadcast_to(rel_pos -> (B, s1, H, T, T)).reshape(B*H, s1, T, T)
// merges NON-adjacent dims (B and H straddle s1=325). C-order arithmetic:
// view (y, n) reads source flat f = (y*325+n)*144 + ... -> source head
// h' = (f/144) % 8 = (325y + n) % 8. For attn row x = 32h+b at position n=p:
// h' = (10400h + 325b + p) % 8 = (5b + p) % 8 = (b*325 + p) % 8 = bp % 8.
// Position-dependent — NOT b % 8. All 8 q-heads share this one bias row.
// ---------------------------------------------------------------------------
template <typename Y_T>
__global__ __launch_bounds__(256) void k3_attn(const Y_T* __restrict__ yq,
                                               const Y_T* __restrict__ yk,
                                               const Y_T* __restrict__ yv,
                                               const float* __restrict__ rel_pos,
                                               const float* __restrict__ Wout,
                                               const float* __restrict__ bout,
                                               float* __restrict__ out) {
  __shared__ __align__(16) float q[12][DD], k[12][DD], v[12][DD], ao[12][DD];
  const int bp = blockIdx.x;
  const size_t base = (size_t)bp * (12 * DD);

  for (int i = threadIdx.x; i < 12 * DD; i += 256) {
    ((float*)q)[i] = ldf(yq + base + i);
    ((float*)k)[i] = ldf(yk + base + i);
    ((float*)v)[i] = ldf(yv + base + i);
  }
  __syncthreads();

  if (threadIdx.x < 96) {  // thread = (head, tq)
    const int h = threadIdx.x / 12, tq = threadIdx.x % 12;
    const float* rp = rel_pos + (size_t)(bp & 7) * 144 + tq * 12;  // head = bp % 8
    float sc[12];
    float mx = -1e30f;
#pragma unroll
    for (int s = 0; s < 12; s++) {
      float d = 0.f;
#pragma unroll
      for (int e = 0; e < 16; e++) d = fmaf(q[tq][h * 16 + e], k[s][h * 16 + e], d);
      d = d * 0.25f + rp[s];  // 1/sqrt(16)
      sc[s] = d;
      mx = fmaxf(mx, d);
    }
    float sum = 0.f;
#pragma unroll
    for (int s = 0; s < 12; s++) { sc[s] = __expf(sc[s] - mx); sum += sc[s]; }
    const float inv = 1.f / sum;
#pragma unroll
    for (int e = 0; e < 16; e++) {
      float o = 0.f;
#pragma unroll
      for (int s = 0; s < 12; s++) o = fmaf(sc[s], v[s][h * 16 + e], o);
      ao[tq][h * 16 + e] = o * inv;
    }
  }
  __syncthreads();

  // projection: out[t][dout] = ao[t][:] . Wout[dout][:] + bout[dout]
  const int dout = threadIdx.x & 127;
  const int tg = threadIdx.x >> 7;  // t in [tg*6, tg*6+6)
  const float* wr = Wout + (size_t)dout * DD;
  float acc[6] = {0.f, 0.f, 0.f, 0.f, 0.f, 0.f};
  for (int d0 = 0; d0 < DD; d0 += 4) {
    const float4 wv = *(const float4*)(wr + d0);
#pragma unroll
    for (int i = 0; i < 6; i++) {
      const float4 av = *(const float4*)(&ao[tg * 6 + i][d0]);  // wave-uniform -> LDS broadcast
      acc[i] = fmaf(av.x, wv.x, fmaf(av.y, wv.y, fmaf(av.z, wv.z, fmaf(av.w, wv.w, acc[i]))));
    }
  }
  const float bo = bout[dout];
#pragma unroll
  for (int i = 0; i < 6; i++) out[base + (size_t)(tg * 6 + i) * DD + dout] = acc[i] + bo;
}

// ---------------------------------------------------------------------------
extern "C" void kernel_launch(void* const* d_in, const int* in_sizes, int n_in,
                              void* d_out, int out_size, void* d_ws, size_t ws_size,
                              hipStream_t stream) {
  (void)in_sizes; (void)n_in; (void)out_size;
  const float* X[3]   = {(const float*)d_in[0], (const float*)d_in[1], (const float*)d_in[2]};
  const float* Wih[3] = {(const float*)d_in[3], (const float*)d_in[7], (const float*)d_in[11]};
  const float* Whh[3] = {(const float*)d_in[4], (const float*)d_in[8], (const float*)d_in[12]};
  const float* bih[3] = {(const float*)d_in[5], (const float*)d_in[9], (const float*)d_in[13]};
  const float* bhh[3] = {(const float*)d_in[6], (const float*)d_in[10], (const float*)d_in[14]};
  const float* rel_pos = (const float*)d_in[15];
  const float* Wout    = (const float*)d_in[16];
  const float* bout    = (const float*)d_in[17];
  float* outp = (float*)d_out;

  const size_t xw_elems    = (size_t)GRU_ROWS * SEQ * D3;  // 47,923,200 (+D3 prefetch slop)
  const size_t y_elems_per = (size_t)GRU_ROWS * SEQ * DD;  // 15,974,400 per GRU
  const size_t slop = D3 * sizeof(float);                  // K2 prefetch overrun guard

  const size_t need_f32   = (xw_elems + 3 * y_elems_per) * sizeof(float) + slop;            // ~366 MiB
  const size_t need_mixed = xw_elems * sizeof(__half) + 3 * y_elems_per * sizeof(float) + slop; // ~275 MiB
  const size_t need_f16   = (xw_elems + 3 * y_elems_per) * sizeof(__half) + slop;           // ~188 MiB

  if (ws_size >= need_f32) {
    float* xw = (float*)d_ws;
    float* y  = xw + xw_elems;
    for (int g = 0; g < 3; g++) {
      k1_inproj<float><<<dim3(975, 6), 256, 0, stream>>>(X[g], Wih[g], bih[g], xw);
      k2_scan<float, float><<<192, 768, 0, stream>>>(xw, Whh[g], bhh[g], y + (size_t)g * y_elems_per);
    }
    k3_attn<float><<<10400, 256, 0, stream>>>(y, y + y_elems_per, y + 2 * y_elems_per,
                                              rel_pos, Wout, bout, outp);
  } else if (ws_size >= need_mixed) {
    // fp16 xw, fp32 y: attention inputs stay full precision
    __half* xw = (__half*)d_ws;
    float*  y  = (float*)(xw + xw_elems);
    for (int g = 0; g < 3; g++) {
      k1_inproj<__half><<<dim3(975, 6), 256, 0, stream>>>(X[g], Wih[g], bih[g], xw);
      k2_scan<__half, float><<<192, 768, 0, stream>>>(xw, Whh[g], bhh[g], y + (size_t)g * y_elems_per);
    }
    k3_attn<float><<<10400, 256, 0, stream>>>(y, y + y_elems_per, y + 2 * y_elems_per,
                                              rel_pos, Wout, bout, outp);
  } else if (ws_size >= need_f16) {
    // all-fp16 intermediates
    __half* xw = (__half*)d_ws;
    __half* y  = xw + xw_elems;
    for (int g = 0; g < 3; g++) {
      k1_inproj<__half><<<dim3(975, 6), 256, 0, stream>>>(X[g], Wih[g], bih[g], xw);
      k2_scan<__half, __half><<<192, 768, 0, stream>>>(xw, Whh[g], bhh[g], y + (size_t)g * y_elems_per);
    }
    k3_attn<__half><<<10400, 256, 0, stream>>>(y, y + y_elems_per, y + 2 * y_elems_per,
                                               rel_pos, Wout, bout, outp);
  }
  // else: ws too small for any correct path — launch nothing (clean validation
  // failure instead of an OOB device fault).
}

// Round 10
// 1948.814 us; speedup vs baseline: 1.0143x; 1.0143x over previous
//
#include <hip/hip_runtime.h>
#include <hip/hip_fp16.h>
#include <cstdint>
#include <cstddef>

// Problem constants: B=32, s1(seq)=325, s2(T)=12, D=128, H=8, hd=16
#define GRU_ROWS 384   // B * s2 = 32*12 independent GRU sequences per GRU
#define SEQ      325   // GRU sequence length (s1)
#define D3       384   // 3*D gate width
#define DD       128   // hidden dim

__device__ __forceinline__ float sigf(float x) { return 1.f / (1.f + __expf(-x)); }
__device__ __forceinline__ float tanh_fast(float x) {
  const float e = __expf(-2.f * fabsf(x));
  const float t = (1.f - e) / (1.f + e);
  return copysignf(t, x);
}

template <typename T> __device__ __forceinline__ float ldf(const T* p);
template <> __device__ __forceinline__ float ldf<float>(const float* p) { return *p; }
template <> __device__ __forceinline__ float ldf<__half>(const __half* p) { return __half2float(*p); }
template <typename T> __device__ __forceinline__ void stf(T* p, float v);
template <> __device__ __forceinline__ void stf<float>(float* p, float v) { *p = v; }
template <> __device__ __forceinline__ void stf<__half>(__half* p, float v) { *p = __float2half(v); }

// ---------------------------------------------------------------------------
// K1: input projection GEMM.  xw[m][g] = sum_d X[m][d]*Wih[g][d] + bih[g]
// X: [124800, 128] row-major; m = row*SEQ + p is the flat storage row.
// Wih: [384, 128] row-major. Tile 128x64, 256 threads, 8x4 outputs each.
// ---------------------------------------------------------------------------
template <typename XW_T>
__global__ __launch_bounds__(256) void k1_inproj(const float* __restrict__ X,
                                                 const float* __restrict__ Wih,
                                                 const float* __restrict__ bih,
                                                 XW_T* __restrict__ xw) {
  __shared__ float As[128][65];  // +1 pad -> conflict-free / 2-way reads
  __shared__ float Bs[64][65];
  const int tid = threadIdx.x;
  const int m0 = blockIdx.x * 128;
  const int n0 = blockIdx.y * 64;
  const int tr = tid >> 4;   // 0..15 -> 8 rows each
  const int tc = tid & 15;   // 0..15 -> 4 cols each
  float acc[8][4] = {};

  for (int kc = 0; kc < 128; kc += 64) {
    __syncthreads();
#pragma unroll
    for (int ps = 0; ps < 8; ps++) {
      const int r = (tid >> 4) + ps * 16;
      const int c = (tid & 15) * 4;
      const float4 a = *(const float4*)(X + (size_t)(m0 + r) * 128 + kc + c);
      As[r][c + 0] = a.x; As[r][c + 1] = a.y; As[r][c + 2] = a.z; As[r][c + 3] = a.w;
    }
#pragma unroll
    for (int ps = 0; ps < 4; ps++) {
      const int r = (tid >> 4) + ps * 16;
      const int c = (tid & 15) * 4;
      const float4 b = *(const float4*)(Wih + (size_t)(n0 + r) * 128 + kc + c);
      Bs[r][c + 0] = b.x; Bs[r][c + 1] = b.y; Bs[r][c + 2] = b.z; Bs[r][c + 3] = b.w;
    }
    __syncthreads();
#pragma unroll 4
    for (int k = 0; k < 64; k++) {
      float a[8], b[4];
#pragma unroll
      for (int i = 0; i < 8; i++) a[i] = As[tr * 8 + i][k];
#pragma unroll
      for (int j = 0; j < 4; j++) b[j] = Bs[tc * 4 + j][k];
#pragma unroll
      for (int i = 0; i < 8; i++)
#pragma unroll
        for (int j = 0; j < 4; j++) acc[i][j] = fmaf(a[i], b[j], acc[i][j]);
    }
  }
  float bi[4];
#pragma unroll
  for (int j = 0; j < 4; j++) bi[j] = bih[n0 + tc * 4 + j];
#pragma unroll
  for (int i = 0; i < 8; i++) {
    XW_T* op = xw + (size_t)(m0 + tr * 8 + i) * D3 + n0 + tc * 4;
#pragma unroll
    for (int j = 0; j < 4; j++) stf(op + j, acc[i][j] + bi[j]);
  }
}

// ---------------------------------------------------------------------------
// K2: sequential GRU scan. Block = 768 threads = 2 rows x 384 gate-threads.
// Thread owns gate g of its row: Whh[g][:] in 128 VGPRs; h broadcast from LDS.
//
// r9 POST-MORTEM: __launch_bounds__(768) alone let the compiler target
// 2 blocks/CU (VGPR cap ~85 -> VGPR_Count=80), DEMOTING w4[32] — Whh was
// re-loaded from global every step (325x): K2=400us, VALUBusy 50%, MfmaUtil 0.
// Fix: min-waves arg = 3 waves/EU -> 1 block/CU -> VGPR cap ~170, w4 stays
// resident (128 + ~30 live ~= 158). Predicted K2 -> 150-220us.
// ---------------------------------------------------------------------------
template <typename XW_T, typename Y_T>
__global__ __launch_bounds__(768, 3) void k2_scan(const XW_T* __restrict__ xw,
                                                  const float* __restrict__ Whh,
                                                  const float* __restrict__ bhh,
                                                  Y_T* __restrict__ y) {
  __shared__ __align__(16) float h_lds[2][DD];
  __shared__ float pre[2][512];
  const int t = threadIdx.x;
  const int sel = (t >= 384) ? 1 : 0;
  const int g = t - sel * 384;
  const int row = blockIdx.x * 2 + sel;
  const int bb = row / 12, jj = row % 12;

  float4 w4[32];
#pragma unroll
  for (int i = 0; i < 32; i++) w4[i] = *(const float4*)(Whh + (size_t)g * DD + i * 4);
  const float bh = bhh[g];
  if (g < DD) h_lds[sel][g] = 0.f;

  const XW_T* xp = xw + (size_t)row * SEQ * D3 + g;
  float xw_cur = ldf(xp);
  Y_T* yp = y + ((size_t)bb * SEQ * 12 + jj) * DD + g;  // used only when g<128
  __syncthreads();

  for (int p = 0; p < SEQ; p++) {
    // Prefetch next step's xw (p=SEQ-1 overrun stays inside d_ws slop).
    const float xw_next = ldf(xp + (size_t)(p + 1) * D3);

    // gh[g] = Whh[g][:] . h  (4 partial chains to break FMA latency)
    const float4* h4 = (const float4*)h_lds[sel];
    float a0 = 0.f, a1 = 0.f, a2 = 0.f, a3 = 0.f;
#pragma unroll
    for (int i = 0; i < 32; i++) {
      const float4 hv = h4[i];
      a0 = fmaf(w4[i].x, hv.x, a0);
      a1 = fmaf(w4[i].y, hv.y, a1);
      a2 = fmaf(w4[i].z, hv.z, a2);
      a3 = fmaf(w4[i].w, hv.w, a3);
    }
    const float hg = (a0 + a1) + (a2 + a3) + bh;

    if (g < 256) {
      pre[sel][g] = xw_cur + hg;          // full preact for r,z
    } else {
      pre[sel][g] = hg;                   // hn (recurrent part incl. bhh)
      pre[sel][g + 128] = xw_cur;         // xn (input part incl. bih)
    }
    __syncthreads();

    if (g < DD) {
      const float r = sigf(pre[sel][g]);
      const float z = sigf(pre[sel][DD + g]);
      const float n = tanh_fast(pre[sel][384 + g] + r * pre[sel][256 + g]);
      const float hold = h_lds[sel][g];
      const float hnew = (1.f - z) * n + z * hold;
      h_lds[sel][g] = hnew;
      stf(yp + (size_t)p * 12 * DD, hnew);
    }
    __syncthreads();
    xw_cur = xw_next;
  }
}

// ---------------------------------------------------------------------------
// K3: attention + output projection, one WG per (b, p). q/k/v/ao staged in LDS.
// Bias head (r7 bug, fixed+verified r9): the reference reshape merges
// non-adjacent dims (B,H straddle s1) -> head = (325*(32h+b)+p) % 8 = bp % 8.
// ---------------------------------------------------------------------------
template <typename Y_T>
__global__ __launch_bounds__(256) void k3_attn(const Y_T* __restrict__ yq,
                                               const Y_T* __restrict__ yk,
                                               const Y_T* __restrict__ yv,
                                               const float* __restrict__ rel_pos,
                                               const float* __restrict__ Wout,
                                               const float* __restrict__ bout,
                                               float* __restrict__ out) {
  __shared__ __align__(16) float q[12][DD], k[12][DD], v[12][DD], ao[12][DD];
  const int bp = blockIdx.x;
  const size_t base = (size_t)bp * (12 * DD);

  for (int i = threadIdx.x; i < 12 * DD; i += 256) {
    ((float*)q)[i] = ldf(yq + base + i);
    ((float*)k)[i] = ldf(yk + base + i);
    ((float*)v)[i] = ldf(yv + base + i);
  }
  __syncthreads();

  if (threadIdx.x < 96) {  // thread = (head, tq)
    const int h = threadIdx.x / 12, tq = threadIdx.x % 12;
    const float* rp = rel_pos + (size_t)(bp & 7) * 144 + tq * 12;  // head = bp % 8
    float sc[12];
    float mx = -1e30f;
#pragma unroll
    for (int s = 0; s < 12; s++) {
      float d = 0.f;
#pragma unroll
      for (int e = 0; e < 16; e++) d = fmaf(q[tq][h * 16 + e], k[s][h * 16 + e], d);
      d = d * 0.25f + rp[s];  // 1/sqrt(16)
      sc[s] = d;
      mx = fmaxf(mx, d);
    }
    float sum = 0.f;
#pragma unroll
    for (int s = 0; s < 12; s++) { sc[s] = __expf(sc[s] - mx); sum += sc[s]; }
    const float inv = 1.f / sum;
#pragma unroll
    for (int e = 0; e < 16; e++) {
      float o = 0.f;
#pragma unroll
      for (int s = 0; s < 12; s++) o = fmaf(sc[s], v[s][h * 16 + e], o);
      ao[tq][h * 16 + e] = o * inv;
    }
  }
  __syncthreads();

  // projection: out[t][dout] = ao[t][:] . Wout[dout][:] + bout[dout]
  const int dout = threadIdx.x & 127;
  const int tg = threadIdx.x >> 7;  // t in [tg*6, tg*6+6)
  const float* wr = Wout + (size_t)dout * DD;
  float acc[6] = {0.f, 0.f, 0.f, 0.f, 0.f, 0.f};
  for (int d0 = 0; d0 < DD; d0 += 4) {
    const float4 wv = *(const float4*)(wr + d0);
#pragma unroll
    for (int i = 0; i < 6; i++) {
      const float4 av = *(const float4*)(&ao[tg * 6 + i][d0]);  // wave-uniform -> LDS broadcast
      acc[i] = fmaf(av.x, wv.x, fmaf(av.y, wv.y, fmaf(av.z, wv.z, fmaf(av.w, wv.w, acc[i]))));
    }
  }
  const float bo = bout[dout];
#pragma unroll
  for (int i = 0; i < 6; i++) out[base + (size_t)(tg * 6 + i) * DD + dout] = acc[i] + bo;
}

// ---------------------------------------------------------------------------
extern "C" void kernel_launch(void* const* d_in, const int* in_sizes, int n_in,
                              void* d_out, int out_size, void* d_ws, size_t ws_size,
                              hipStream_t stream) {
  (void)in_sizes; (void)n_in; (void)out_size;
  const float* X[3]   = {(const float*)d_in[0], (const float*)d_in[1], (const float*)d_in[2]};
  const float* Wih[3] = {(const float*)d_in[3], (const float*)d_in[7], (const float*)d_in[11]};
  const float* Whh[3] = {(const float*)d_in[4], (const float*)d_in[8], (const float*)d_in[12]};
  const float* bih[3] = {(const float*)d_in[5], (const float*)d_in[9], (const float*)d_in[13]};
  const float* bhh[3] = {(const float*)d_in[6], (const float*)d_in[10], (const float*)d_in[14]};
  const float* rel_pos = (const float*)d_in[15];
  const float* Wout    = (const float*)d_in[16];
  const float* bout    = (const float*)d_in[17];
  float* outp = (float*)d_out;

  const size_t xw_elems    = (size_t)GRU_ROWS * SEQ * D3;  // 47,923,200 (+D3 prefetch slop)
  const size_t y_elems_per = (size_t)GRU_ROWS * SEQ * DD;  // 15,974,400 per GRU
  const size_t slop = D3 * sizeof(float);                  // K2 prefetch overrun guard

  const size_t need_f32   = (xw_elems + 3 * y_elems_per) * sizeof(float) + slop;            // ~366 MiB
  const size_t need_mixed = xw_elems * sizeof(__half) + 3 * y_elems_per * sizeof(float) + slop; // ~275 MiB
  const size_t need_f16   = (xw_elems + 3 * y_elems_per) * sizeof(__half) + slop;           // ~188 MiB

  if (ws_size >= need_f32) {
    float* xw = (float*)d_ws;
    float* y  = xw + xw_elems;
    for (int g = 0; g < 3; g++) {
      k1_inproj<float><<<dim3(975, 6), 256, 0, stream>>>(X[g], Wih[g], bih[g], xw);
      k2_scan<float, float><<<192, 768, 0, stream>>>(xw, Whh[g], bhh[g], y + (size_t)g * y_elems_per);
    }
    k3_attn<float><<<10400, 256, 0, stream>>>(y, y + y_elems_per, y + 2 * y_elems_per,
                                              rel_pos, Wout, bout, outp);
  } else if (ws_size >= need_mixed) {
    // fp16 xw, fp32 y: attention inputs stay full precision
    __half* xw = (__half*)d_ws;
    float*  y  = (float*)(xw + xw_elems);
    for (int g = 0; g < 3; g++) {
      k1_inproj<__half><<<dim3(975, 6), 256, 0, stream>>>(X[g], Wih[g], bih[g], xw);
      k2_scan<__half, float><<<192, 768, 0, stream>>>(xw, Whh[g], bhh[g], y + (size_t)g * y_elems_per);
    }
    k3_attn<float><<<10400, 256, 0, stream>>>(y, y + y_elems_per, y + 2 * y_elems_per,
                                              rel_pos, Wout, bout, outp);
  } else if (ws_size >= need_f16) {
    // all-fp16 intermediates
    __half* xw = (__half*)d_ws;
    __half* y  = xw + xw_elems;
    for (int g = 0; g < 3; g++) {
      k1_inproj<__half><<<dim3(975, 6), 256, 0, stream>>>(X[g], Wih[g], bih[g], xw);
      k2_scan<__half, __half><<<192, 768, 0, stream>>>(xw, Whh[g], bhh[g], y + (size_t)g * y_elems_per);
    }
    k3_attn<__half><<<10400, 256, 0, stream>>>(y, y + y_elems_per, y + 2 * y_elems_per,
                                               rel_pos, Wout, bout, outp);
  }
  // else: ws too small for any correct path — launch nothing (clean validation
  // failure instead of an OOB device fault).
}